// Round 6
// baseline (511.215 us; speedup 1.0000x reference)
//
#include <hip/hip_runtime.h>
#include <math.h>

#define NN 100000
#define NE 3200000
#define NBKT 782            // ceil(100000 / 128) buckets of 128 dst nodes
#define NCB 256             // count/scatter blocks
#define CAP 4608            // max edges staged per bucket (mean 4092 -> +8 sigma)

// ---------------- helpers ----------------

__device__ __forceinline__ uint2 ntload_u2(const uint2* p) {
    unsigned long long v = __builtin_nontemporal_load((const unsigned long long*)p);
    return make_uint2((unsigned)(v & 0xffffffffu), (unsigned)(v >> 32));
}

// ---------------- small init ----------------

__global__ void k_zero_scal(float* __restrict__ scal) {
    if (threadIdx.x < 32) scal[threadIdx.x] = 0.0f;
}

// ---------------- bucket build (no global atomics) ----------------

__global__ void k_count(const int* __restrict__ dst, int* __restrict__ counts) {
    __shared__ int hist[NBKT];
    for (int t = threadIdx.x; t < NBKT; t += 256) hist[t] = 0;
    __syncthreads();
    for (int e = blockIdx.x * 256 + threadIdx.x; e < NE; e += NCB * 256)
        atomicAdd(&hist[__builtin_nontemporal_load(&dst[e]) >> 7], 1);
    __syncthreads();
    for (int t = threadIdx.x; t < NBKT; t += 256)
        counts[blockIdx.x * NBKT + t] = hist[t];
}

__global__ void k_colsum(const int* __restrict__ counts, int* __restrict__ total) {
    int bin = blockIdx.x * 256 + threadIdx.x;
    if (bin >= NBKT) return;
    int s = 0;
    for (int b = 0; b < NCB; ++b) s += counts[b * NBKT + bin];
    total[bin] = s;
}

__global__ void k_scan(const int* __restrict__ total, int* __restrict__ start) {
    __shared__ int a[1024];
    int t = threadIdx.x;
    int mine = (t < NBKT) ? total[t] : 0;
    a[t] = mine;
    for (int off = 1; off < 1024; off <<= 1) {
        __syncthreads();
        int v = a[t] + ((t >= off) ? a[t - off] : 0);
        __syncthreads();
        a[t] = v;
    }
    __syncthreads();
    if (t < NBKT) start[t] = a[t] - mine;        // exclusive
    if (t == 0) start[NBKT] = NE;
}

__global__ void k_base(const int* __restrict__ counts, const int* __restrict__ start,
                       int* __restrict__ base) {
    int bin = blockIdx.x * 256 + threadIdx.x;
    if (bin >= NBKT) return;
    int run = start[bin];
    for (int b = 0; b < NCB; ++b) {
        base[b * NBKT + bin] = run;
        run += counts[b * NBKT + bin];
    }
}

// scatter edge records (src<<7 | dstloc, w) into bucket order
__global__ void k_scatter(const int* __restrict__ src, const int* __restrict__ dst,
                          const float* __restrict__ w, const int* __restrict__ base,
                          uint2* __restrict__ rec) {
    __shared__ int cur[NBKT];
    for (int t = threadIdx.x; t < NBKT; t += 256)
        cur[t] = base[blockIdx.x * NBKT + t];
    __syncthreads();
    for (int e = blockIdx.x * 256 + threadIdx.x; e < NE; e += NCB * 256) {
        int d = __builtin_nontemporal_load(&dst[e]);
        int s = __builtin_nontemporal_load(&src[e]);
        float we = __builtin_nontemporal_load(&w[e]);
        int bin = d >> 7;
        int pos = atomicAdd(&cur[bin], 1);
        rec[pos] = make_uint2(((unsigned)s << 7) | (unsigned)(d & 127),
                              __float_as_uint(we));
    }
}

// ---------------- degree / dinv (per bucket, LDS atomics) ----------------

__global__ void k_deg(const uint2* __restrict__ rec, const int* __restrict__ start,
                      float* __restrict__ dinv) {
    __shared__ float dacc[128];
    int bin = blockIdx.x;
    if (threadIdx.x < 128) dacc[threadIdx.x] = 0.0f;
    __syncthreads();
    int e0 = start[bin], e1 = start[bin + 1];
    for (int j = e0 + threadIdx.x; j < e1; j += 256) {
        uint2 r = ntload_u2(&rec[j]);
        atomicAdd(&dacc[r.x & 127], __uint_as_float(r.y));
    }
    __syncthreads();
    int node = (bin << 7) + threadIdx.x;
    if (threadIdx.x < 128 && node < NN)
        dinv[node] = rsqrtf(1.0f + dacc[threadIdx.x]);   // deg >= 1 (self-loop)
}

// ---------------- in-place within-bucket counting sort -> CSR ----------------

__global__ void k_sort(uint2* __restrict__ rec, const int* __restrict__ start,
                       const float* __restrict__ dinv, int* __restrict__ nodeptr) {
    __shared__ uint2 buf[CAP];       // 36 KB staging
    __shared__ int hist[128];
    __shared__ int scn[128];
    __shared__ int cur[128];
    __shared__ float dloc[128];
    int bin = blockIdx.x;
    int base_node = bin << 7;
    int nNodes = min(128, NN - base_node);
    int e0 = start[bin], e1 = start[bin + 1];
    int cnt = e1 - e0;
    if (cnt > CAP) cnt = CAP;
    if (threadIdx.x < 128) {
        hist[threadIdx.x] = 0;
        dloc[threadIdx.x] = (threadIdx.x < nNodes) ? dinv[base_node + threadIdx.x] : 0.0f;
    }
    __syncthreads();
    for (int j = threadIdx.x; j < cnt; j += 256) {
        uint2 r = ntload_u2(&rec[e0 + j]);
        buf[j] = r;
        atomicAdd(&hist[r.x & 127], 1);
    }
    __syncthreads();
    if (threadIdx.x < 128) scn[threadIdx.x] = hist[threadIdx.x];
    __syncthreads();
    for (int off = 1; off < 128; off <<= 1) {
        int v = 0;
        if (threadIdx.x < 128) {
            v = scn[threadIdx.x];
            if (threadIdx.x >= off) v += scn[threadIdx.x - off];
        }
        __syncthreads();
        if (threadIdx.x < 128) scn[threadIdx.x] = v;
        __syncthreads();
    }
    if (threadIdx.x < 128) {
        int excl = scn[threadIdx.x] - hist[threadIdx.x];
        cur[threadIdx.x] = excl;
        if (threadIdx.x < nNodes) nodeptr[base_node + threadIdx.x] = e0 + excl;
    }
    if (bin == NBKT - 1 && threadIdx.x == 0) nodeptr[NN] = e1;   // == NE
    __syncthreads();
    for (int j = threadIdx.x; j < cnt; j += 256) {
        uint2 r = buf[j];
        int s = (int)(r.x >> 7);
        int dl = r.x & 127;
        int pos = atomicAdd(&cur[dl], 1);
        float nw = dinv[s] * __uint_as_float(r.y) * dloc[dl];
        rec[e0 + pos] = make_uint2((unsigned)s, __float_as_uint(nw));
    }
}

// ---------------- dense transform layer 1 (LDS-staged, coalesced) ----------------
// 64 rows per block; grid 1563

__global__ __launch_bounds__(256) void k_xform64(const float* __restrict__ x,
                                                 const float* __restrict__ W,
                                                 float* __restrict__ out) {
    __shared__ float xs[64 * 68];    // 64 rows x 64 cols, pad 4
    __shared__ float Wsh[16 * 68];
    int row0 = blockIdx.x * 64;
    for (int idx = threadIdx.x; idx < 1024; idx += 256)
        Wsh[(idx >> 6) * 68 + (idx & 63)] = W[idx];
    for (int idx = threadIdx.x; idx < 1024; idx += 256) {   // 1024 float4 loads
        int r = idx >> 4, c4 = idx & 15;
        float4 v = make_float4(0.f, 0.f, 0.f, 0.f);
        if (row0 + r < NN)
            v = *(const float4*)(x + (size_t)(row0 + r) * 64 + c4 * 4);
        *(float4*)&xs[r * 68 + c4 * 4] = v;
    }
    __syncthreads();
    int f = threadIdx.x & 15, rg = threadIdx.x >> 4;   // rg 0..15 -> rows rg*4..+3
    float a0 = 0.f, a1 = 0.f, a2 = 0.f, a3 = 0.f;
#pragma unroll
    for (int k4 = 0; k4 < 16; ++k4) {
        float4 wv = *(float4*)&Wsh[f * 68 + k4 * 4];
        float4 x0 = *(float4*)&xs[(rg * 4 + 0) * 68 + k4 * 4];
        float4 x1 = *(float4*)&xs[(rg * 4 + 1) * 68 + k4 * 4];
        float4 x2 = *(float4*)&xs[(rg * 4 + 2) * 68 + k4 * 4];
        float4 x3 = *(float4*)&xs[(rg * 4 + 3) * 68 + k4 * 4];
        a0 += x0.x * wv.x + x0.y * wv.y + x0.z * wv.z + x0.w * wv.w;
        a1 += x1.x * wv.x + x1.y * wv.y + x1.z * wv.z + x1.w * wv.w;
        a2 += x2.x * wv.x + x2.y * wv.y + x2.z * wv.z + x2.w * wv.w;
        a3 += x3.x * wv.x + x3.y * wv.y + x3.z * wv.z + x3.w * wv.w;
    }
    int br = row0 + rg * 4;
    if (br + 0 < NN) out[(br + 0) * 16 + f] = a0;
    if (br + 1 < NN) out[(br + 1) * 16 + f] = a1;
    if (br + 2 < NN) out[(br + 2) * 16 + f] = a2;
    if (br + 3 < NN) out[(br + 3) * 16 + f] = a3;
}

// ---------------- layer 1: CSR agg + fused relu + W2 transform ----------------
// bufC[n][f] = sum_k relu(o1[n][k]) * W2[f][k],  o1 = b1 + dinv^2 h + sum norm*h[src]

__global__ __launch_bounds__(256) void k_agg16_l1(const uint2* __restrict__ rec,
                                                  const int* __restrict__ nodeptr,
                                                  const float* __restrict__ dinv,
                                                  const float* __restrict__ h,
                                                  const float* __restrict__ b1,
                                                  const float* __restrict__ W2,
                                                  float* __restrict__ outC) {
    __shared__ float W2s[16 * 17];
    for (int idx = threadIdx.x; idx < 256; idx += 256)
        W2s[(idx >> 4) * 17 + (idx & 15)] = W2[idx];
    __syncthreads();
    int f = threadIdx.x & 15;
    int n = blockIdx.x * 16 + (threadIdx.x >> 4);
    int e0 = nodeptr[n], e1 = nodeptr[n + 1];
    float di = dinv[n];
    float acc = b1[f] + di * di * h[n * 16 + f];
    int j = e0;
    for (; j + 4 <= e1; j += 4) {
        uint2 r0 = ntload_u2(&rec[j]),     r1 = ntload_u2(&rec[j + 1]);
        uint2 r2 = ntload_u2(&rec[j + 2]), r3 = ntload_u2(&rec[j + 3]);
        float h0 = h[r0.x * 16 + f];
        float h1 = h[r1.x * 16 + f];
        float h2 = h[r2.x * 16 + f];
        float h3 = h[r3.x * 16 + f];
        acc += __uint_as_float(r0.y) * h0;
        acc += __uint_as_float(r1.y) * h1;
        acc += __uint_as_float(r2.y) * h2;
        acc += __uint_as_float(r3.y) * h3;
    }
    for (; j < e1; ++j) {
        uint2 r = ntload_u2(&rec[j]);
        acc += __uint_as_float(r.y) * h[r.x * 16 + f];
    }
    float rl = fmaxf(acc, 0.0f);
    float a2 = 0.0f;
#pragma unroll
    for (int k = 0; k < 16; ++k)
        a2 += __shfl(rl, k, 16) * W2s[f * 17 + k];
    outC[n * 16 + f] = a2;     // coalesced
}

// ---------------- layer 2: CSR agg + fused relu + W3 dot + pool ----------------
// No dense output written: clin[n] = relu(o2[n]) . W3 ; hsum += relu(o2) per feat

__global__ __launch_bounds__(256) void k_agg16_l2(const uint2* __restrict__ rec,
                                                  const int* __restrict__ nodeptr,
                                                  const float* __restrict__ dinv,
                                                  const float* __restrict__ h,
                                                  const float* __restrict__ b2,
                                                  const float* __restrict__ W3,
                                                  float* __restrict__ clin,
                                                  float* __restrict__ hsum) {
    __shared__ float lds[256];
    int f = threadIdx.x & 15;
    int n = blockIdx.x * 16 + (threadIdx.x >> 4);
    int e0 = nodeptr[n], e1 = nodeptr[n + 1];
    float di = dinv[n];
    float acc = b2[f] + di * di * h[n * 16 + f];
    int j = e0;
    for (; j + 4 <= e1; j += 4) {
        uint2 r0 = ntload_u2(&rec[j]),     r1 = ntload_u2(&rec[j + 1]);
        uint2 r2 = ntload_u2(&rec[j + 2]), r3 = ntload_u2(&rec[j + 3]);
        float h0 = h[r0.x * 16 + f];
        float h1 = h[r1.x * 16 + f];
        float h2 = h[r2.x * 16 + f];
        float h3 = h[r3.x * 16 + f];
        acc += __uint_as_float(r0.y) * h0;
        acc += __uint_as_float(r1.y) * h1;
        acc += __uint_as_float(r2.y) * h2;
        acc += __uint_as_float(r3.y) * h3;
    }
    for (; j < e1; ++j) {
        uint2 r = ntload_u2(&rec[j]);
        acc += __uint_as_float(r.y) * h[r.x * 16 + f];
    }
    float rl = fmaxf(acc, 0.0f);
    // clin[n] = sum_f rl * W3[f]  (16-lane reduce)
    float s = rl * W3[f];
    s += __shfl_xor(s, 8, 16);
    s += __shfl_xor(s, 4, 16);
    s += __shfl_xor(s, 2, 16);
    s += __shfl_xor(s, 1, 16);
    if (f == 0) clin[n] = s;
    // pool partial: per-block sum of rl per feature
    lds[threadIdx.x] = rl;
    __syncthreads();
    for (int st = 128; st >= 16; st >>= 1) {
        if (threadIdx.x < st) lds[threadIdx.x] += lds[threadIdx.x + st];
        __syncthreads();
    }
    if (threadIdx.x < 16) atomicAdd(&hsum[threadIdx.x], lds[threadIdx.x]);
}

// ---------------- layer 3 scalar aggregation ----------------

__global__ void k_aggc(const uint2* __restrict__ rec, const int* __restrict__ nodeptr,
                       const float* __restrict__ dinv, const float* __restrict__ clin,
                       const float* __restrict__ b3, float* __restrict__ c) {
    int lane = threadIdx.x & 7;
    int n = blockIdx.x * 32 + (threadIdx.x >> 3);
    int e0 = nodeptr[n], e1 = nodeptr[n + 1];
    float acc = 0.0f;
    for (int j = e0 + lane; j < e1; j += 8) {
        uint2 r = ntload_u2(&rec[j]);
        acc += __uint_as_float(r.y) * clin[r.x];
    }
    acc += __shfl_down(acc, 4, 8);
    acc += __shfl_down(acc, 2, 8);
    acc += __shfl_down(acc, 1, 8);
    if (lane == 0) {
        float di = dinv[n];
        c[n] = b3[0] + di * di * clin[n] + acc;
    }
}

// ---------------- softmax ----------------

__device__ __forceinline__ unsigned fkey(float x) {
    unsigned b = __float_as_uint(x);
    return (b & 0x80000000u) ? ~b : (b | 0x80000000u);
}
__device__ __forceinline__ float fdecode(unsigned u) {
    unsigned b = (u & 0x80000000u) ? (u & 0x7FFFFFFFu) : ~u;
    return __uint_as_float(b);
}

__global__ void k_max(const float* __restrict__ c, unsigned* __restrict__ maxkey) {
    __shared__ float lds[256];
    float m = -INFINITY;
    for (int i = blockIdx.x * 256 + threadIdx.x; i < NN; i += gridDim.x * 256)
        m = fmaxf(m, c[i]);
    lds[threadIdx.x] = m;
    __syncthreads();
    for (int s = 128; s > 0; s >>= 1) {
        if (threadIdx.x < s) lds[threadIdx.x] = fmaxf(lds[threadIdx.x], lds[threadIdx.x + s]);
        __syncthreads();
    }
    if (threadIdx.x == 0) atomicMax(maxkey, fkey(lds[0]));
}

__global__ void k_exp(const float* __restrict__ c, const unsigned* __restrict__ maxkey,
                      float* __restrict__ outp, float* __restrict__ sumexp) {
    __shared__ float lds[256];
    float mx = fdecode(*maxkey);
    float s = 0.0f;
    for (int i = blockIdx.x * 256 + threadIdx.x; i < NN; i += gridDim.x * 256) {
        float p = expf(c[i] - mx);
        outp[i] = p;
        s += p;
    }
    lds[threadIdx.x] = s;
    __syncthreads();
    for (int t = 128; t > 0; t >>= 1) {
        if (threadIdx.x < t) lds[threadIdx.x] += lds[threadIdx.x + t];
        __syncthreads();
    }
    if (threadIdx.x == 0) atomicAdd(sumexp, lds[0]);
}

__global__ void k_final(float* __restrict__ out, const float* __restrict__ sumexp,
                        const float* __restrict__ hsum, const float* __restrict__ A2w,
                        const float* __restrict__ A2b) {
    float inv = 1.0f / (*sumexp);
    for (int i = blockIdx.x * 256 + threadIdx.x; i < NN; i += gridDim.x * 256)
        out[i] *= inv;
    if (blockIdx.x == 0 && threadIdx.x == 0) {
        float v = 0.0f;
#pragma unroll
        for (int f = 0; f < 16; ++f) v += hsum[f] * (1.0f / (float)NN) * A2w[f];
        out[NN] = v + A2b[0];
    }
}

// ---------------- launch ----------------

extern "C" void kernel_launch(void* const* d_in, const int* in_sizes, int n_in,
                              void* d_out, int out_size, void* d_ws, size_t ws_size,
                              hipStream_t stream) {
    const float* x   = (const float*)d_in[0];
    const int*   src = (const int*)d_in[1];
    const int*   dst = ((const int*)d_in[1]) + NE;
    const float* w   = (const float*)d_in[2];
    const float* W1  = (const float*)d_in[3];
    const float* b1  = (const float*)d_in[4];
    const float* W2  = (const float*)d_in[5];
    const float* b2  = (const float*)d_in[6];
    const float* W3  = (const float*)d_in[7];
    const float* b3  = (const float*)d_in[8];
    const float* A2w = (const float*)d_in[9];
    const float* A2b = (const float*)d_in[10];
    float* out = (float*)d_out;

    // workspace layout (floats)
    float* ws     = (float*)d_ws;
    uint2* rec    = (uint2*)ws;                 // NE uint2 (25.6 MB), CSR in place
    float* dinv   = ws + 2 * (size_t)NE;        // NN
    float* bufA   = dinv + NN;                  // NN*16 (xform64 out)
    float* bufC   = bufA + NN * 16;             // NN*16 (layer-1 fused out)
    float* clin   = bufC + NN * 16;             // NN
    float* cbuf   = clin + NN;                  // NN
    float* scal   = cbuf + NN;                  // 32: [0]=maxkey [1]=sumexp [2..17]=hsum
    int*   total  = (int*)(scal + 32);          // NBKT
    int*   startb = total + NBKT;               // NBKT+1
    int*   nodeptr= startb + NBKT + 1;          // NN+1
    // counts/base alias bufC (dead until agg16_l1 writes it)
    int*   counts = (int*)bufC;                 // NCB*NBKT
    int*   basea  = counts + NCB * NBKT;        // NCB*NBKT

    // bucket build + degree + CSR sort
    k_zero_scal<<<1, 64, 0, stream>>>(scal);
    k_count<<<NCB, 256, 0, stream>>>(dst, counts);
    k_colsum<<<(NBKT + 255) / 256, 256, 0, stream>>>(counts, total);
    k_scan<<<1, 1024, 0, stream>>>(total, startb);
    k_base<<<(NBKT + 255) / 256, 256, 0, stream>>>(counts, startb, basea);
    k_scatter<<<NCB, 256, 0, stream>>>(src, dst, w, basea, rec);
    k_deg<<<NBKT, 256, 0, stream>>>(rec, startb, dinv);
    k_sort<<<NBKT, 256, 0, stream>>>(rec, startb, dinv, nodeptr);

    // layer 1 dense (LDS-staged)
    k_xform64<<<(NN + 63) / 64, 256, 0, stream>>>(x, W1, bufA);
    // layer 1 agg + fused relu+W2 transform
    k_agg16_l1<<<NN / 16, 256, 0, stream>>>(rec, nodeptr, dinv, bufA, b1, W2, bufC);
    // layer 2 agg + fused relu + W3 dot + pool (no dense output)
    k_agg16_l2<<<NN / 16, 256, 0, stream>>>(rec, nodeptr, dinv, bufC, b2, W3, clin, scal + 2);
    // layer 3 scalar agg
    k_aggc<<<NN / 32, 256, 0, stream>>>(rec, nodeptr, dinv, clin, b3, cbuf);

    // softmax + value
    k_max<<<512, 256, 0, stream>>>(cbuf, (unsigned*)scal);
    k_exp<<<512, 256, 0, stream>>>(cbuf, (const unsigned*)scal, out, scal + 1);
    k_final<<<512, 256, 0, stream>>>(out, scal + 1, scal + 2, A2w, A2b);
}